// Round 9
// baseline (222.241 us; speedup 1.0000x reference)
//
#include <hip/hip_runtime.h>
#include <hip/hip_bf16.h>

// ---------------------------------------------------------------------------
// SemanticActor fused forward, bf16 MFMA (gfx950) — Round 9
// R8 arithmetic: MFMA 42us, LDS 52us per kernel; LDS dominates and barriers
// serialize. Dominant LDS term = H B-frag reads: 8 waves x full H = 8x read
// amplification. R9: wave remap 8 col-slices -> 4 col-groups(64 cols) x
// 2 row-sets(32 rows): each hf read feeds 4 MFMAs -> GEMM2/3 reads halve.
// w2f[8][4]=128 VGPR OK (1 block/CU pinned -> ~256 VGPR/wave real budget).
// GEMM1 in i-halves caps transient pressure. No W1P prefetch (R8: spilled,
// no gain). Everything else (layouts, buffers, barriers, prep) = R8.
// ---------------------------------------------------------------------------

#define B_TOTAL 65536
#define TROWS   64
#define RSTR    136   // rawS row stride elems: 272B = 17x16B -> optimal b128 phasing

typedef __attribute__((ext_vector_type(8))) short s8v;   // 8 x bf16
typedef __attribute__((ext_vector_type(4))) float f4v;   // MFMA C/D

__constant__ int c_PI[6] = {0,0,1,1,2,2};
__constant__ int c_PJ[6] = {1,2,0,2,0,1};
__constant__ int c_PF[6] = {0,0,1,0,1,1};
// inverse of FIRST_INDS / SECOND_INDS: raw ag/g col -> X col (or -1)
__constant__ int c_INV[2][30] = {
  {0,1,2,3,4,5,6,7,8,9,10,11,12,13,-1,14,15,16,-1,-1,17,18,-1,-1,-1,19,-1,-1,-1,-1},
  {0,1,2,3,4,5,6,7,8,9,-1,-1,-1,-1,10,-1,-1,-1,11,12,-1,-1,13,14,15,-1,16,17,18,19}};

static __device__ __forceinline__ short bf16s(float v) {
  __hip_bfloat16 h = __float2bfloat16(v);
  union { __hip_bfloat16 h; short s; } u; u.h = h; return u.s;
}

// ---- prep: one 512-elem fragment per wave; coalesced reads, b128 writes ----
__global__ __launch_bounds__(256)
void prep_weights(const float* __restrict__ phi_w1,
                  const float* __restrict__ phi_b1,
                  const float* __restrict__ phi_w2,
                  const float* __restrict__ rho_w1,
                  const float* __restrict__ mean_w,
                  const float* __restrict__ logstd_w,
                  __hip_bfloat16* __restrict__ W1P,
                  __hip_bfloat16* __restrict__ W2f,
                  __hip_bfloat16* __restrict__ W3f,
                  __hip_bfloat16* __restrict__ W4f) {
  const int wid  = (blockIdx.x * blockDim.x + threadIdx.x) >> 6;
  const int lane = threadIdx.x & 63;
  const int l15  = lane & 15;
  const int kq   = (lane >> 4) * 8;
  if (wid >= 648) return;
  union { short s[8]; s8v v; } o;
  __hip_bfloat16* dst;
  if (wid < 384) {
    const int p = wid >> 6, rem = wid & 63;
    const int nb = rem >> 2, ks = rem & 3;
    const int n = nb * 16 + l15;
    const int f = c_PF[p], oi = c_PI[p], oj = c_PJ[p];
#pragma unroll
    for (int j = 0; j < 8; ++j) {
      int k = ks * 32 + kq + j;
      float v = 0.0f;
      if (k < 30)       { int t = c_INV[f][k];      if (t >= 0) v = phi_w1[t * 256 + n]; }
      else if (k < 60)  { int t = c_INV[f][k - 30]; if (t >= 0) v = phi_w1[(30 + t) * 256 + n]; }
      else if (k < 70)  { v = phi_w1[(20 + k - 60) * 256 + n]; }
      else if (k < 115) { int q = (k - 70) / 15, t = (k - 70) - q * 15;
                          int c = (q == oi) ? 50 + t : (q == oj) ? 65 + t : -1;
                          if (c >= 0) v = phi_w1[c * 256 + n]; }
      else if (k == 115) v = phi_b1[n];   // bias via ones-column
      o.s[j] = bf16s(v);
    }
    dst = W1P + wid * 512 + lane * 8;
  } else if (wid < 512) {
    const int r = wid - 384;
    const int nb = r >> 3, ks = r & 7;
    const int n = nb * 16 + l15;
#pragma unroll
    for (int j = 0; j < 8; ++j)
      o.s[j] = bf16s(phi_w2[(ks * 32 + kq + j) * 256 + n]);
    dst = W2f + r * 512 + lane * 8;
  } else if (wid < 640) {
    const int r = wid - 512;
    const int nb = r >> 3, ks = r & 7;
    const int n = nb * 16 + l15;
#pragma unroll
    for (int j = 0; j < 8; ++j)
      o.s[j] = bf16s(rho_w1[(ks * 32 + kq + j) * 256 + n]);
    dst = W3f + r * 512 + lane * 8;
  } else {
    const int ks = wid - 640;
    const int n = l15;
#pragma unroll
    for (int j = 0; j < 8; ++j) {
      int k = ks * 32 + kq + j;
      float v = (n < 4) ? mean_w[k * 4 + n]
              : (n < 8) ? logstd_w[k * 4 + (n - 4)] : 0.0f;
      o.s[j] = bf16s(v);
    }
    dst = W4f + ks * 512 + lane * 8;
  }
  *reinterpret_cast<s8v*>(dst) = o.v;
}

static __device__ __forceinline__ unsigned pk2(float a, float b) {
  __hip_bfloat162 h = __float22bfloat162_rn(float2{a, b});
  union { __hip_bfloat162 h2; unsigned u; } cv; cv.h2 = h;
  return cv.u;
}

// ---- main: 512 threads (8 waves), 64 rows/block ----------------------------
// wave -> cg = w&3 (64 hidden cols: i=0..3 over cols cg*64+i*16),
//         rs = w>>2 (32 batch rows: rg = rs*2+rt, rt=0..1)
__global__ __launch_bounds__(512, 2)
void actor_main(const float* __restrict__ obs, const float* __restrict__ ag,
                const float* __restrict__ g,
                const __hip_bfloat16* __restrict__ W1P,
                const __hip_bfloat16* __restrict__ W2f,
                const __hip_bfloat16* __restrict__ W3f,
                const __hip_bfloat16* __restrict__ W4f,
                const float* __restrict__ b2, const float* __restrict__ b3,
                const float* __restrict__ meanb,
                const float* __restrict__ logstdb,
                float* __restrict__ out) {
  __shared__ __align__(16) __hip_bfloat16 rawS[TROWS * RSTR];      // 17.4 KB
  __shared__ __align__(16) __hip_bfloat16 HsBuf[2][4 * 8 * 512];   // 64 KB

  const int tid  = threadIdx.x;
  const int lane = tid & 63;
  const int w    = tid >> 6;
  const int cg   = w & 3;        // col group: 64 cols [cg*64, cg*64+64)
  const int rs   = w >> 2;       // row set:   32 rows [rs*32, rs*32+32)
  const int l15  = lane & 15;
  const int quad = lane >> 4;
  const int r0   = blockIdx.x * TROWS;

  // biases per col-16 slice i (cols cg*64 + i*16 + quad*4 + r)
  float4 b2v[4];
#pragma unroll
  for (int i = 0; i < 4; ++i)
    b2v[i] = *(const float4*)&b2[cg * 64 + i * 16 + quad * 4];

  // persistent W2 fragments: 64 cols x 256 K = 128 VGPR (once per block)
  s8v w2f[8][4];
#pragma unroll
  for (int i = 0; i < 4; ++i)
#pragma unroll
    for (int ks = 0; ks < 8; ++ks)
      w2f[ks][i] = *(const s8v*)&W2f[(((cg * 4 + i) * 8 + ks) * 512) + lane * 8];

  // stage raw input [ag|g|obs|1|0] bf16 K=128 (2 b128 stores/thread)
  {
    const int row = tid >> 3;
    const int c0  = (tid & 7) * 16;
    const float* agr = ag  + (size_t)(r0 + row) * 30;
    const float* gr  = g   + (size_t)(r0 + row) * 30;
    const float* obr = obs + (size_t)(r0 + row) * 55;
    union { short s[16]; s8v v[2]; } o;
#pragma unroll
    for (int cc = 0; cc < 16; ++cc) {
      int c = c0 + cc;
      float v;
      if      (c < 30)  v = agr[c];
      else if (c < 60)  v = gr[c - 30];
      else if (c < 115) v = obr[c - 60];
      else if (c == 115) v = 1.0f;
      else              v = 0.0f;
      o.s[cc] = bf16s(v);
    }
    *reinterpret_cast<s8v*>(&rawS[row * RSTR + c0])     = o.v[0];
    *reinterpret_cast<s8v*>(&rawS[row * RSTR + c0 + 8]) = o.v[1];
  }

  f4v agg[4][2];
#pragma unroll
  for (int i = 0; i < 4; ++i)
#pragma unroll
    for (int rt = 0; rt < 2; ++rt) agg[i][rt] = f4v{0.f, 0.f, 0.f, 0.f};

  const int ebase = l15 * 8 + (quad >> 1) * 128 + (quad & 1) * 4;

  __syncthreads();  // rawS staged

#pragma unroll 1
  for (int p = 0; p < 6; ++p) {
    __hip_bfloat16* buf = &HsBuf[p & 1][0];
    const __hip_bfloat16* w1base = W1P + p * 32768;

    // GEMM1 in i-halves (caps transient VGPRs): h = W1P[p](A) x raw(B); K=128
#pragma unroll 1
    for (int ih = 0; ih < 2; ++ih) {
      s8v w1f[4][2];
#pragma unroll
      for (int il = 0; il < 2; ++il)
#pragma unroll
        for (int ks = 0; ks < 4; ++ks)
          w1f[ks][il] = *(const s8v*)&w1base[(((cg * 4 + ih * 2 + il) * 4 + ks) * 512) + lane * 8];
      f4v h[2][2];
#pragma unroll
      for (int il = 0; il < 2; ++il)
#pragma unroll
        for (int rt = 0; rt < 2; ++rt) h[il][rt] = f4v{0.f, 0.f, 0.f, 0.f};
#pragma unroll
      for (int ks = 0; ks < 4; ++ks) {
        s8v bx[2];
#pragma unroll
        for (int rt = 0; rt < 2; ++rt)
          bx[rt] = *(const s8v*)&rawS[((rs * 2 + rt) * 16 + l15) * RSTR + ks * 32 + quad * 8];
#pragma unroll
        for (int il = 0; il < 2; ++il)
#pragma unroll
          for (int rt = 0; rt < 2; ++rt)
            h[il][rt] = __builtin_amdgcn_mfma_f32_16x16x32_bf16(w1f[ks][il], bx[rt], h[il][rt], 0, 0, 0);
      }
      // epilogue: relu (bias folded via ones-column), pack -> b64 writes
#pragma unroll
      for (int il = 0; il < 2; ++il)
#pragma unroll
        for (int rt = 0; rt < 2; ++rt) {
          float v0 = fmaxf(h[il][rt][0], 0.f);
          float v1 = fmaxf(h[il][rt][1], 0.f);
          float v2 = fmaxf(h[il][rt][2], 0.f);
          float v3 = fmaxf(h[il][rt][3], 0.f);
          uint2 U; U.x = pk2(v0, v1); U.y = pk2(v2, v3);
          *reinterpret_cast<uint2*>(
            &buf[((rs * 2 + rt) * 8 + cg * 2 + ih) * 512 + il * 256 + ebase]) = U;
        }
    }
    __syncthreads();  // H(p) complete; other buffer's readers fenced by prev barrier

    // GEMM2: a2 = W2(A) x H(B); K=256; agg += relu(a2 + b2)
    f4v a2[4][2];
#pragma unroll
    for (int i = 0; i < 4; ++i)
#pragma unroll
      for (int rt = 0; rt < 2; ++rt) a2[i][rt] = f4v{0.f, 0.f, 0.f, 0.f};
#pragma unroll
    for (int ks = 0; ks < 8; ++ks) {
      s8v hf[2];
#pragma unroll
      for (int rt = 0; rt < 2; ++rt)
        hf[rt] = *(const s8v*)&buf[((rs * 2 + rt) * 8 + ks) * 512 + lane * 8];
#pragma unroll
      for (int i = 0; i < 4; ++i)
#pragma unroll
        for (int rt = 0; rt < 2; ++rt)
          a2[i][rt] = __builtin_amdgcn_mfma_f32_16x16x32_bf16(w2f[ks][i], hf[rt], a2[i][rt], 0, 0, 0);
    }
#pragma unroll
    for (int i = 0; i < 4; ++i)
#pragma unroll
      for (int rt = 0; rt < 2; ++rt) {
        agg[i][rt][0] += fmaxf(a2[i][rt][0] + b2v[i].x, 0.f);
        agg[i][rt][1] += fmaxf(a2[i][rt][1] + b2v[i].y, 0.f);
        agg[i][rt][2] += fmaxf(a2[i][rt][2] + b2v[i].z, 0.f);
        agg[i][rt][3] += fmaxf(a2[i][rt][3] + b2v[i].w, 0.f);
      }
  }

  // W3 frags + b3 (w2f dead, registers reused)
  s8v w3f[8][4];
#pragma unroll
  for (int i = 0; i < 4; ++i)
#pragma unroll
    for (int ks = 0; ks < 8; ++ks)
      w3f[ks][i] = *(const s8v*)&W3f[(((cg * 4 + i) * 8 + ks) * 512) + lane * 8];
  float4 b3v[4];
#pragma unroll
  for (int i = 0; i < 4; ++i)
    b3v[i] = *(const float4*)&b3[cg * 64 + i * 16 + quad * 4];

  // stash agg (bf16) into buf0 (its last readers fenced by p=5 barrier)
  {
    __hip_bfloat16* bufA = &HsBuf[0][0];
#pragma unroll
    for (int i = 0; i < 4; ++i)
#pragma unroll
      for (int rt = 0; rt < 2; ++rt) {
        uint2 U; U.x = pk2(agg[i][rt][0], agg[i][rt][1]);
        U.y = pk2(agg[i][rt][2], agg[i][rt][3]);
        *reinterpret_cast<uint2*>(
          &bufA[((rs * 2 + rt) * 8 + cg * 2 + (i >> 1)) * 512 + (i & 1) * 256 + ebase]) = U;
      }
  }
  __syncthreads();

  // GEMM3: hr = relu(W3(A) x agg(B) + b3); reads buf0, writes buf1
  f4v a3[4][2];
#pragma unroll
  for (int i = 0; i < 4; ++i)
#pragma unroll
    for (int rt = 0; rt < 2; ++rt) a3[i][rt] = f4v{0.f, 0.f, 0.f, 0.f};
  {
    const __hip_bfloat16* bufA = &HsBuf[0][0];
#pragma unroll
    for (int ks = 0; ks < 8; ++ks) {
      s8v hf[2];
#pragma unroll
      for (int rt = 0; rt < 2; ++rt)
        hf[rt] = *(const s8v*)&bufA[((rs * 2 + rt) * 8 + ks) * 512 + lane * 8];
#pragma unroll
      for (int i = 0; i < 4; ++i)
#pragma unroll
        for (int rt = 0; rt < 2; ++rt)
          a3[i][rt] = __builtin_amdgcn_mfma_f32_16x16x32_bf16(w3f[ks][i], hf[rt], a3[i][rt], 0, 0, 0);
    }
  }
  {
    __hip_bfloat16* bufB = &HsBuf[1][0];
#pragma unroll
    for (int i = 0; i < 4; ++i)
#pragma unroll
      for (int rt = 0; rt < 2; ++rt) {
        float v0 = fmaxf(a3[i][rt][0] + b3v[i].x, 0.f);
        float v1 = fmaxf(a3[i][rt][1] + b3v[i].y, 0.f);
        float v2 = fmaxf(a3[i][rt][2] + b3v[i].z, 0.f);
        float v3 = fmaxf(a3[i][rt][3] + b3v[i].w, 0.f);
        uint2 U; U.x = pk2(v0, v1); U.y = pk2(v2, v3);
        *reinterpret_cast<uint2*>(
          &bufB[((rs * 2 + rt) * 8 + cg * 2 + (i >> 1)) * 512 + (i & 1) * 256 + ebase]) = U;
      }
  }
  __syncthreads();

  // GEMM4: heads; waves 0..3 take 16-row group rg=w; reads buf1
  if (w < 4) {
    const __hip_bfloat16* bufB = &HsBuf[1][0];
    f4v a4 = f4v{0.f, 0.f, 0.f, 0.f};
#pragma unroll
    for (int ks = 0; ks < 8; ++ks) {
      s8v w4 = *(const s8v*)&W4f[ks * 512 + lane * 8];
      s8v hf = *(const s8v*)&bufB[(w * 8 + ks) * 512 + lane * 8];
      a4 = __builtin_amdgcn_mfma_f32_16x16x32_bf16(w4, hf, a4, 0, 0, 0);
    }
    const int row = r0 + w * 16 + l15;
    if (quad == 0) {          // head cols 0..3 = mean
      float4 mb = *(const float4*)meanb;
      float4 o;
      o.x = a4[0] + mb.x; o.y = a4[1] + mb.y;
      o.z = a4[2] + mb.z; o.w = a4[3] + mb.w;
      *reinterpret_cast<float4*>(&out[(size_t)row * 4]) = o;
    } else if (quad == 1) {   // head cols 4..7 = logstd (clipped)
      float4 lb = *(const float4*)logstdb;
      float4 o;
      o.x = fminf(fmaxf(a4[0] + lb.x, -20.f), 2.f);
      o.y = fminf(fmaxf(a4[1] + lb.y, -20.f), 2.f);
      o.z = fminf(fmaxf(a4[2] + lb.z, -20.f), 2.f);
      o.w = fminf(fmaxf(a4[3] + lb.w, -20.f), 2.f);
      *reinterpret_cast<float4*>(&out[(size_t)B_TOTAL * 4 + (size_t)row * 4]) = o;
    }
  }
}

extern "C" void kernel_launch(void* const* d_in, const int* in_sizes, int n_in,
                              void* d_out, int out_size, void* d_ws, size_t ws_size,
                              hipStream_t stream) {
  const float* obs      = (const float*)d_in[0];
  const float* ag       = (const float*)d_in[1];
  const float* g        = (const float*)d_in[2];
  const float* phi_w1   = (const float*)d_in[3];
  const float* phi_b1   = (const float*)d_in[4];
  const float* phi_w2   = (const float*)d_in[5];
  const float* phi_b2   = (const float*)d_in[6];
  const float* rho_w1   = (const float*)d_in[7];
  const float* rho_b1   = (const float*)d_in[8];
  const float* mean_w   = (const float*)d_in[9];
  const float* mean_b   = (const float*)d_in[10];
  const float* logstd_w = (const float*)d_in[11];
  const float* logstd_b = (const float*)d_in[12];
  float* out = (float*)d_out;

  // ws (bf16): W1P 6x32768 | W2f 65536 | W3f 65536 | W4f 4096 elems
  char* ws = (char*)d_ws;
  __hip_bfloat16* W1P = (__hip_bfloat16*)(ws);
  __hip_bfloat16* W2f = (__hip_bfloat16*)(ws + 393216);
  __hip_bfloat16* W3f = (__hip_bfloat16*)(ws + 393216 + 131072);
  __hip_bfloat16* W4f = (__hip_bfloat16*)(ws + 393216 + 262144);

  prep_weights<<<162, 256, 0, stream>>>(phi_w1, phi_b1, phi_w2, rho_w1,
                                        mean_w, logstd_w, W1P, W2f, W3f, W4f);
  actor_main<<<B_TOTAL / TROWS, 512, 0, stream>>>(
      obs, ag, g, W1P, W2f, W3f, W4f, phi_b2, rho_b1, mean_b, logstd_b, out);
}

// Round 10
// 219.558 us; speedup vs baseline: 1.0122x; 1.0122x over previous
//
#include <hip/hip_runtime.h>
#include <hip/hip_bf16.h>

// ---------------------------------------------------------------------------
// SemanticActor fused forward, bf16 MFMA (gfx950) — Round 10
// R9 post-mortem: the 64-col/32-row wave remap (LDS B-frag reads halved) was
// right, but (512,2) caps VGPR at 128 in this toolchain (R4/R7/R8/R9 all show
// VGPR_Count=128 + scratch traffic); R9 needs ~190 persistent VGPR -> the
// accumulators spilled inside the K-loop (WRITE 38MB). (512,1) allows 256
// (R5: 108 used, no spill). R10 = R9 with __launch_bounds__(512,1).
// Budget: w2f[8][4]=128 + agg=32 + a2=32 persistent, ~235 peak <= 256; still
// 2 waves/SIMD (8 waves/CU) so residency unchanged.
// ---------------------------------------------------------------------------

#define B_TOTAL 65536
#define TROWS   64
#define RSTR    136   // rawS row stride elems: 272B = 17x16B -> optimal b128 phasing

typedef __attribute__((ext_vector_type(8))) short s8v;   // 8 x bf16
typedef __attribute__((ext_vector_type(4))) float f4v;   // MFMA C/D

__constant__ int c_PI[6] = {0,0,1,1,2,2};
__constant__ int c_PJ[6] = {1,2,0,2,0,1};
__constant__ int c_PF[6] = {0,0,1,0,1,1};
// inverse of FIRST_INDS / SECOND_INDS: raw ag/g col -> X col (or -1)
__constant__ int c_INV[2][30] = {
  {0,1,2,3,4,5,6,7,8,9,10,11,12,13,-1,14,15,16,-1,-1,17,18,-1,-1,-1,19,-1,-1,-1,-1},
  {0,1,2,3,4,5,6,7,8,9,-1,-1,-1,-1,10,-1,-1,-1,11,12,-1,-1,13,14,15,-1,16,17,18,19}};

static __device__ __forceinline__ short bf16s(float v) {
  __hip_bfloat16 h = __float2bfloat16(v);
  union { __hip_bfloat16 h; short s; } u; u.h = h; return u.s;
}

// ---- prep: one 512-elem fragment per wave; coalesced reads, b128 writes ----
__global__ __launch_bounds__(256)
void prep_weights(const float* __restrict__ phi_w1,
                  const float* __restrict__ phi_b1,
                  const float* __restrict__ phi_w2,
                  const float* __restrict__ rho_w1,
                  const float* __restrict__ mean_w,
                  const float* __restrict__ logstd_w,
                  __hip_bfloat16* __restrict__ W1P,
                  __hip_bfloat16* __restrict__ W2f,
                  __hip_bfloat16* __restrict__ W3f,
                  __hip_bfloat16* __restrict__ W4f) {
  const int wid  = (blockIdx.x * blockDim.x + threadIdx.x) >> 6;
  const int lane = threadIdx.x & 63;
  const int l15  = lane & 15;
  const int kq   = (lane >> 4) * 8;
  if (wid >= 648) return;
  union { short s[8]; s8v v; } o;
  __hip_bfloat16* dst;
  if (wid < 384) {
    const int p = wid >> 6, rem = wid & 63;
    const int nb = rem >> 2, ks = rem & 3;
    const int n = nb * 16 + l15;
    const int f = c_PF[p], oi = c_PI[p], oj = c_PJ[p];
#pragma unroll
    for (int j = 0; j < 8; ++j) {
      int k = ks * 32 + kq + j;
      float v = 0.0f;
      if (k < 30)       { int t = c_INV[f][k];      if (t >= 0) v = phi_w1[t * 256 + n]; }
      else if (k < 60)  { int t = c_INV[f][k - 30]; if (t >= 0) v = phi_w1[(30 + t) * 256 + n]; }
      else if (k < 70)  { v = phi_w1[(20 + k - 60) * 256 + n]; }
      else if (k < 115) { int q = (k - 70) / 15, t = (k - 70) - q * 15;
                          int c = (q == oi) ? 50 + t : (q == oj) ? 65 + t : -1;
                          if (c >= 0) v = phi_w1[c * 256 + n]; }
      else if (k == 115) v = phi_b1[n];   // bias via ones-column
      o.s[j] = bf16s(v);
    }
    dst = W1P + wid * 512 + lane * 8;
  } else if (wid < 512) {
    const int r = wid - 384;
    const int nb = r >> 3, ks = r & 7;
    const int n = nb * 16 + l15;
#pragma unroll
    for (int j = 0; j < 8; ++j)
      o.s[j] = bf16s(phi_w2[(ks * 32 + kq + j) * 256 + n]);
    dst = W2f + r * 512 + lane * 8;
  } else if (wid < 640) {
    const int r = wid - 512;
    const int nb = r >> 3, ks = r & 7;
    const int n = nb * 16 + l15;
#pragma unroll
    for (int j = 0; j < 8; ++j)
      o.s[j] = bf16s(rho_w1[(ks * 32 + kq + j) * 256 + n]);
    dst = W3f + r * 512 + lane * 8;
  } else {
    const int ks = wid - 640;
    const int n = l15;
#pragma unroll
    for (int j = 0; j < 8; ++j) {
      int k = ks * 32 + kq + j;
      float v = (n < 4) ? mean_w[k * 4 + n]
              : (n < 8) ? logstd_w[k * 4 + (n - 4)] : 0.0f;
      o.s[j] = bf16s(v);
    }
    dst = W4f + ks * 512 + lane * 8;
  }
  *reinterpret_cast<s8v*>(dst) = o.v;
}

static __device__ __forceinline__ unsigned pk2(float a, float b) {
  __hip_bfloat162 h = __float22bfloat162_rn(float2{a, b});
  union { __hip_bfloat162 h2; unsigned u; } cv; cv.h2 = h;
  return cv.u;
}

// ---- main: 512 threads (8 waves), 64 rows/block ----------------------------
// wave -> cg = w&3 (64 hidden cols: i=0..3 over cols cg*64+i*16),
//         rs = w>>2 (32 batch rows: rg = rs*2+rt, rt=0..1)
__global__ __launch_bounds__(512, 1)
void actor_main(const float* __restrict__ obs, const float* __restrict__ ag,
                const float* __restrict__ g,
                const __hip_bfloat16* __restrict__ W1P,
                const __hip_bfloat16* __restrict__ W2f,
                const __hip_bfloat16* __restrict__ W3f,
                const __hip_bfloat16* __restrict__ W4f,
                const float* __restrict__ b2, const float* __restrict__ b3,
                const float* __restrict__ meanb,
                const float* __restrict__ logstdb,
                float* __restrict__ out) {
  __shared__ __align__(16) __hip_bfloat16 rawS[TROWS * RSTR];      // 17.4 KB
  __shared__ __align__(16) __hip_bfloat16 HsBuf[2][4 * 8 * 512];   // 64 KB

  const int tid  = threadIdx.x;
  const int lane = tid & 63;
  const int w    = tid >> 6;
  const int cg   = w & 3;        // col group: 64 cols [cg*64, cg*64+64)
  const int rs   = w >> 2;       // row set:   32 rows [rs*32, rs*32+32)
  const int l15  = lane & 15;
  const int quad = lane >> 4;
  const int r0   = blockIdx.x * TROWS;

  // biases per col-16 slice i (cols cg*64 + i*16 + quad*4 + r)
  float4 b2v[4];
#pragma unroll
  for (int i = 0; i < 4; ++i)
    b2v[i] = *(const float4*)&b2[cg * 64 + i * 16 + quad * 4];

  // persistent W2 fragments: 64 cols x 256 K = 128 VGPR (once per block)
  s8v w2f[8][4];
#pragma unroll
  for (int i = 0; i < 4; ++i)
#pragma unroll
    for (int ks = 0; ks < 8; ++ks)
      w2f[ks][i] = *(const s8v*)&W2f[(((cg * 4 + i) * 8 + ks) * 512) + lane * 8];

  // stage raw input [ag|g|obs|1|0] bf16 K=128 (2 b128 stores/thread)
  {
    const int row = tid >> 3;
    const int c0  = (tid & 7) * 16;
    const float* agr = ag  + (size_t)(r0 + row) * 30;
    const float* gr  = g   + (size_t)(r0 + row) * 30;
    const float* obr = obs + (size_t)(r0 + row) * 55;
    union { short s[16]; s8v v[2]; } o;
#pragma unroll
    for (int cc = 0; cc < 16; ++cc) {
      int c = c0 + cc;
      float v;
      if      (c < 30)  v = agr[c];
      else if (c < 60)  v = gr[c - 30];
      else if (c < 115) v = obr[c - 60];
      else if (c == 115) v = 1.0f;
      else              v = 0.0f;
      o.s[cc] = bf16s(v);
    }
    *reinterpret_cast<s8v*>(&rawS[row * RSTR + c0])     = o.v[0];
    *reinterpret_cast<s8v*>(&rawS[row * RSTR + c0 + 8]) = o.v[1];
  }

  f4v agg[4][2];
#pragma unroll
  for (int i = 0; i < 4; ++i)
#pragma unroll
    for (int rt = 0; rt < 2; ++rt) agg[i][rt] = f4v{0.f, 0.f, 0.f, 0.f};

  const int ebase = l15 * 8 + (quad >> 1) * 128 + (quad & 1) * 4;

  __syncthreads();  // rawS staged

#pragma unroll 1
  for (int p = 0; p < 6; ++p) {
    __hip_bfloat16* buf = &HsBuf[p & 1][0];
    const __hip_bfloat16* w1base = W1P + p * 32768;

    // GEMM1 in i-halves (caps transient VGPRs): h = W1P[p](A) x raw(B); K=128
#pragma unroll 1
    for (int ih = 0; ih < 2; ++ih) {
      s8v w1f[4][2];
#pragma unroll
      for (int il = 0; il < 2; ++il)
#pragma unroll
        for (int ks = 0; ks < 4; ++ks)
          w1f[ks][il] = *(const s8v*)&w1base[(((cg * 4 + ih * 2 + il) * 4 + ks) * 512) + lane * 8];
      f4v h[2][2];
#pragma unroll
      for (int il = 0; il < 2; ++il)
#pragma unroll
        for (int rt = 0; rt < 2; ++rt) h[il][rt] = f4v{0.f, 0.f, 0.f, 0.f};
#pragma unroll
      for (int ks = 0; ks < 4; ++ks) {
        s8v bx[2];
#pragma unroll
        for (int rt = 0; rt < 2; ++rt)
          bx[rt] = *(const s8v*)&rawS[((rs * 2 + rt) * 16 + l15) * RSTR + ks * 32 + quad * 8];
#pragma unroll
        for (int il = 0; il < 2; ++il)
#pragma unroll
          for (int rt = 0; rt < 2; ++rt)
            h[il][rt] = __builtin_amdgcn_mfma_f32_16x16x32_bf16(w1f[ks][il], bx[rt], h[il][rt], 0, 0, 0);
      }
      // epilogue: relu (bias folded via ones-column), pack -> b64 writes
#pragma unroll
      for (int il = 0; il < 2; ++il)
#pragma unroll
        for (int rt = 0; rt < 2; ++rt) {
          float v0 = fmaxf(h[il][rt][0], 0.f);
          float v1 = fmaxf(h[il][rt][1], 0.f);
          float v2 = fmaxf(h[il][rt][2], 0.f);
          float v3 = fmaxf(h[il][rt][3], 0.f);
          uint2 U; U.x = pk2(v0, v1); U.y = pk2(v2, v3);
          *reinterpret_cast<uint2*>(
            &buf[((rs * 2 + rt) * 8 + cg * 2 + ih) * 512 + il * 256 + ebase]) = U;
        }
    }
    __syncthreads();  // H(p) complete; other buffer's readers fenced by prev barrier

    // GEMM2: a2 = W2(A) x H(B); K=256; agg += relu(a2 + b2)
    f4v a2[4][2];
#pragma unroll
    for (int i = 0; i < 4; ++i)
#pragma unroll
      for (int rt = 0; rt < 2; ++rt) a2[i][rt] = f4v{0.f, 0.f, 0.f, 0.f};
#pragma unroll
    for (int ks = 0; ks < 8; ++ks) {
      s8v hf[2];
#pragma unroll
      for (int rt = 0; rt < 2; ++rt)
        hf[rt] = *(const s8v*)&buf[((rs * 2 + rt) * 8 + ks) * 512 + lane * 8];
#pragma unroll
      for (int i = 0; i < 4; ++i)
#pragma unroll
        for (int rt = 0; rt < 2; ++rt)
          a2[i][rt] = __builtin_amdgcn_mfma_f32_16x16x32_bf16(w2f[ks][i], hf[rt], a2[i][rt], 0, 0, 0);
    }
#pragma unroll
    for (int i = 0; i < 4; ++i)
#pragma unroll
      for (int rt = 0; rt < 2; ++rt) {
        agg[i][rt][0] += fmaxf(a2[i][rt][0] + b2v[i].x, 0.f);
        agg[i][rt][1] += fmaxf(a2[i][rt][1] + b2v[i].y, 0.f);
        agg[i][rt][2] += fmaxf(a2[i][rt][2] + b2v[i].z, 0.f);
        agg[i][rt][3] += fmaxf(a2[i][rt][3] + b2v[i].w, 0.f);
      }
  }

  // W3 frags + b3 (w2f dead, registers reused)
  s8v w3f[8][4];
#pragma unroll
  for (int i = 0; i < 4; ++i)
#pragma unroll
    for (int ks = 0; ks < 8; ++ks)
      w3f[ks][i] = *(const s8v*)&W3f[(((cg * 4 + i) * 8 + ks) * 512) + lane * 8];
  float4 b3v[4];
#pragma unroll
  for (int i = 0; i < 4; ++i)
    b3v[i] = *(const float4*)&b3[cg * 64 + i * 16 + quad * 4];

  // stash agg (bf16) into buf0 (its last readers fenced by p=5 barrier)
  {
    __hip_bfloat16* bufA = &HsBuf[0][0];
#pragma unroll
    for (int i = 0; i < 4; ++i)
#pragma unroll
      for (int rt = 0; rt < 2; ++rt) {
        uint2 U; U.x = pk2(agg[i][rt][0], agg[i][rt][1]);
        U.y = pk2(agg[i][rt][2], agg[i][rt][3]);
        *reinterpret_cast<uint2*>(
          &bufA[((rs * 2 + rt) * 8 + cg * 2 + (i >> 1)) * 512 + (i & 1) * 256 + ebase]) = U;
      }
  }
  __syncthreads();

  // GEMM3: hr = relu(W3(A) x agg(B) + b3); reads buf0, writes buf1
  f4v a3[4][2];
#pragma unroll
  for (int i = 0; i < 4; ++i)
#pragma unroll
    for (int rt = 0; rt < 2; ++rt) a3[i][rt] = f4v{0.f, 0.f, 0.f, 0.f};
  {
    const __hip_bfloat16* bufA = &HsBuf[0][0];
#pragma unroll
    for (int ks = 0; ks < 8; ++ks) {
      s8v hf[2];
#pragma unroll
      for (int rt = 0; rt < 2; ++rt)
        hf[rt] = *(const s8v*)&bufA[((rs * 2 + rt) * 8 + ks) * 512 + lane * 8];
#pragma unroll
      for (int i = 0; i < 4; ++i)
#pragma unroll
        for (int rt = 0; rt < 2; ++rt)
          a3[i][rt] = __builtin_amdgcn_mfma_f32_16x16x32_bf16(w3f[ks][i], hf[rt], a3[i][rt], 0, 0, 0);
    }
  }
  {
    __hip_bfloat16* bufB = &HsBuf[1][0];
#pragma unroll
    for (int i = 0; i < 4; ++i)
#pragma unroll
      for (int rt = 0; rt < 2; ++rt) {
        float v0 = fmaxf(a3[i][rt][0] + b3v[i].x, 0.f);
        float v1 = fmaxf(a3[i][rt][1] + b3v[i].y, 0.f);
        float v2 = fmaxf(a3[i][rt][2] + b3v[i].z, 0.f);
        float v3 = fmaxf(a3[i][rt][3] + b3v[i].w, 0.f);
        uint2 U; U.x = pk2(v0, v1); U.y = pk2(v2, v3);
        *reinterpret_cast<uint2*>(
          &bufB[((rs * 2 + rt) * 8 + cg * 2 + (i >> 1)) * 512 + (i & 1) * 256 + ebase]) = U;
      }
  }
  __syncthreads();

  // GEMM4: heads; waves 0..3 take 16-row group rg=w; reads buf1
  if (w < 4) {
    const __hip_bfloat16* bufB = &HsBuf[1][0];
    f4v a4 = f4v{0.f, 0.f, 0.f, 0.f};
#pragma unroll
    for (int ks = 0; ks < 8; ++ks) {
      s8v w4 = *(const s8v*)&W4f[ks * 512 + lane * 8];
      s8v hf = *(const s8v*)&bufB[(w * 8 + ks) * 512 + lane * 8];
      a4 = __builtin_amdgcn_mfma_f32_16x16x32_bf16(w4, hf, a4, 0, 0, 0);
    }
    const int row = r0 + w * 16 + l15;
    if (quad == 0) {          // head cols 0..3 = mean
      float4 mb = *(const float4*)meanb;
      float4 o;
      o.x = a4[0] + mb.x; o.y = a4[1] + mb.y;
      o.z = a4[2] + mb.z; o.w = a4[3] + mb.w;
      *reinterpret_cast<float4*>(&out[(size_t)row * 4]) = o;
    } else if (quad == 1) {   // head cols 4..7 = logstd (clipped)
      float4 lb = *(const float4*)logstdb;
      float4 o;
      o.x = fminf(fmaxf(a4[0] + lb.x, -20.f), 2.f);
      o.y = fminf(fmaxf(a4[1] + lb.y, -20.f), 2.f);
      o.z = fminf(fmaxf(a4[2] + lb.z, -20.f), 2.f);
      o.w = fminf(fmaxf(a4[3] + lb.w, -20.f), 2.f);
      *reinterpret_cast<float4*>(&out[(size_t)B_TOTAL * 4 + (size_t)row * 4]) = o;
    }
  }
}

extern "C" void kernel_launch(void* const* d_in, const int* in_sizes, int n_in,
                              void* d_out, int out_size, void* d_ws, size_t ws_size,
                              hipStream_t stream) {
  const float* obs      = (const float*)d_in[0];
  const float* ag       = (const float*)d_in[1];
  const float* g        = (const float*)d_in[2];
  const float* phi_w1   = (const float*)d_in[3];
  const float* phi_b1   = (const float*)d_in[4];
  const float* phi_w2   = (const float*)d_in[5];
  const float* phi_b2   = (const float*)d_in[6];
  const float* rho_w1   = (const float*)d_in[7];
  const float* rho_b1   = (const float*)d_in[8];
  const float* mean_w   = (const float*)d_in[9];
  const float* mean_b   = (const float*)d_in[10];
  const float* logstd_w = (const float*)d_in[11];
  const float* logstd_b = (const float*)d_in[12];
  float* out = (float*)d_out;

  // ws (bf16): W1P 6x32768 | W2f 65536 | W3f 65536 | W4f 4096 elems
  char* ws = (char*)d_ws;
  __hip_bfloat16* W1P = (__hip_bfloat16*)(ws);
  __hip_bfloat16* W2f = (__hip_bfloat16*)(ws + 393216);
  __hip_bfloat16* W3f = (__hip_bfloat16*)(ws + 393216 + 131072);
  __hip_bfloat16* W4f = (__hip_bfloat16*)(ws + 393216 + 262144);

  prep_weights<<<162, 256, 0, stream>>>(phi_w1, phi_b1, phi_w2, rho_w1,
                                        mean_w, logstd_w, W1P, W2f, W3f, W4f);
  actor_main<<<B_TOTAL / TROWS, 512, 0, stream>>>(
      obs, ag, g, W1P, W2f, W3f, W4f, phi_b2, rho_b1, mean_b, logstd_b, out);
}

// Round 11
// 189.320 us; speedup vs baseline: 1.1739x; 1.1597x over previous
//
#include <hip/hip_runtime.h>
#include <hip/hip_bf16.h>

// ---------------------------------------------------------------------------
// SemanticActor fused forward — Round 11: 32x32x16 MFMA rewrite.
// R10 null settled: 128 = arch-VGPR cap (accumulators live in AGPRs).
// R5 tiling (32 cols/wave, 64 arch VGPR of weights) is register-optimal;
// levers left: instruction count + issue slots. 32x32x16 does 2x FLOP/instr
// (8.07 vs 4.85 cyc): MFMA pipe -17%, issue slots halve, epilogue LDS writes
// halve (C/D reg-quads cover 4 consecutive k). 1 barrier/pair: body =
// GEMM2(p); GEMM1(p+1)->other buffer (no barrier between -> L2/MFMA of
// GEMM1 overlaps LDS of GEMM2).
// Layouts: A[m=lane&31][k=8*(lane>>5)+j]; C/D col=lane&31,
// row=(reg&3)+8*(reg>>2)+4*(lane>>5) [m74/m101]. Activations stored B-frag-
// major (1KB blocks; elem(n,k) at (n+32*(k>>3))*8+(k&7)) -> all LDS accesses
// are lane-contiguous b128.
// ---------------------------------------------------------------------------

#define B_TOTAL 65536
#define TROWS   64

typedef __attribute__((ext_vector_type(8)))  short s8v;   // 8 x bf16
typedef __attribute__((ext_vector_type(16))) float f16v;  // 32x32 C/D

__constant__ int c_PI[6] = {0,0,1,1,2,2};
__constant__ int c_PJ[6] = {1,2,0,2,0,1};
__constant__ int c_PF[6] = {0,0,1,0,1,1};
__constant__ int c_INV[2][30] = {
  {0,1,2,3,4,5,6,7,8,9,10,11,12,13,-1,14,15,16,-1,-1,17,18,-1,-1,-1,19,-1,-1,-1,-1},
  {0,1,2,3,4,5,6,7,8,9,-1,-1,-1,-1,10,-1,-1,-1,11,12,-1,-1,13,14,15,-1,16,17,18,19}};

static __device__ __forceinline__ short bf16s(float v) {
  __hip_bfloat16 h = __float2bfloat16(v);
  union { __hip_bfloat16 h; short s; } u; u.h = h; return u.s;
}
static __device__ __forceinline__ unsigned pk2(float a, float b) {
  __hip_bfloat162 h = __float22bfloat162_rn(float2{a, b});
  union { __hip_bfloat162 h2; unsigned u; } cv; cv.h2 = h;
  return cv.u;
}

// ---- prep: 656 wave-tasks, one 1KB A-frag block each; coalesced ------------
// [0,384) W1P: p=wid>>6, mt=(wid&63)>>3, ks=wid&7  (8 mt x 8 ks per pair)
// [384,512) W2f: mt=r>>4, ks=r&15   [512,640) W3f   [640,656) W4f: ks
__global__ __launch_bounds__(256)
void prep_weights(const float* __restrict__ phi_w1,
                  const float* __restrict__ phi_b1,
                  const float* __restrict__ phi_w2,
                  const float* __restrict__ rho_w1,
                  const float* __restrict__ mean_w,
                  const float* __restrict__ logstd_w,
                  __hip_bfloat16* __restrict__ W1P,
                  __hip_bfloat16* __restrict__ W2f,
                  __hip_bfloat16* __restrict__ W3f,
                  __hip_bfloat16* __restrict__ W4f) {
  const int wid  = (blockIdx.x * blockDim.x + threadIdx.x) >> 6;
  const int lane = threadIdx.x & 63;
  const int l31  = lane & 31;
  const int kq   = (lane >> 5) * 8;
  if (wid >= 656) return;
  union { short s[8]; s8v v; } o;
  __hip_bfloat16* dst;
  if (wid < 384) {
    const int p = wid >> 6, rem = wid & 63;
    const int n = ((rem >> 3) * 32) + l31;        // out col 0..255
    const int ksb = (rem & 7) * 16;
    const int f = c_PF[p], oi = c_PI[p], oj = c_PJ[p];
#pragma unroll
    for (int j = 0; j < 8; ++j) {
      int k = ksb + kq + j;                        // raw dim 0..127
      float v = 0.0f;
      if (k < 30)       { int t = c_INV[f][k];      if (t >= 0) v = phi_w1[t * 256 + n]; }
      else if (k < 60)  { int t = c_INV[f][k - 30]; if (t >= 0) v = phi_w1[(30 + t) * 256 + n]; }
      else if (k < 70)  { v = phi_w1[(20 + k - 60) * 256 + n]; }
      else if (k < 115) { int q = (k - 70) / 15, t = (k - 70) - q * 15;
                          int c = (q == oi) ? 50 + t : (q == oj) ? 65 + t : -1;
                          if (c >= 0) v = phi_w1[c * 256 + n]; }
      else if (k == 115) v = phi_b1[n];   // bias via ones-column
      o.s[j] = bf16s(v);
    }
    dst = W1P + wid * 512 + lane * 8;
  } else if (wid < 512) {
    const int r = wid - 384;
    const int n = ((r >> 4) * 32) + l31;
    const int ksb = (r & 15) * 16;
#pragma unroll
    for (int j = 0; j < 8; ++j)
      o.s[j] = bf16s(phi_w2[(ksb + kq + j) * 256 + n]);
    dst = W2f + r * 512 + lane * 8;
  } else if (wid < 640) {
    const int r = wid - 512;
    const int n = ((r >> 4) * 32) + l31;
    const int ksb = (r & 15) * 16;
#pragma unroll
    for (int j = 0; j < 8; ++j)
      o.s[j] = bf16s(rho_w1[(ksb + kq + j) * 256 + n]);
    dst = W3f + r * 512 + lane * 8;
  } else {
    const int ks = wid - 640;
    const int n = l31;                      // head col: <4 mean, <8 logstd
#pragma unroll
    for (int j = 0; j < 8; ++j) {
      int k = ks * 16 + kq + j;
      float v = (n < 4) ? mean_w[k * 4 + n]
              : (n < 8) ? logstd_w[k * 4 + (n - 4)] : 0.0f;
      o.s[j] = bf16s(v);
    }
    dst = W4f + ks * 512 + lane * 8;
  }
  *reinterpret_cast<s8v*>(dst) = o.v;
}

// ---- main: 512 threads (8 waves), 64 rows/block; wave w = 32 out cols ------
__global__ __launch_bounds__(512, 1)
void actor_main(const float* __restrict__ obs, const float* __restrict__ ag,
                const float* __restrict__ g,
                const __hip_bfloat16* __restrict__ W1P,
                const __hip_bfloat16* __restrict__ W2f,
                const __hip_bfloat16* __restrict__ W3f,
                const __hip_bfloat16* __restrict__ W4f,
                const float* __restrict__ b2, const float* __restrict__ b3,
                const float* __restrict__ meanb,
                const float* __restrict__ logstdb,
                float* __restrict__ out) {
  // raw: blocks (nt 0..1, ks 0..7) of 512 elems; H: 2 buffers x (nt, ks 0..15)
  __shared__ __align__(16) __hip_bfloat16 rawS[2 * 8 * 512];       // 16 KB
  __shared__ __align__(16) __hip_bfloat16 Hs[2][2 * 16 * 512];     // 64 KB

  const int tid  = threadIdx.x;
  const int lane = tid & 63;
  const int w    = tid >> 6;
  const int l31  = lane & 31;
  const int q5   = lane >> 5;
  const int r0   = blockIdx.x * TROWS;

  // biases: col = w*32 + 8*g + 4*q5 + r
  float4 b2v[4];
#pragma unroll
  for (int gidx = 0; gidx < 4; ++gidx)
    b2v[gidx] = *(const float4*)&b2[w * 32 + 8 * gidx + 4 * q5];

  // persistent W2 A-frags: 16 ksteps x 4 VGPR = 64 arch
  s8v w2f[16];
#pragma unroll
  for (int ks = 0; ks < 16; ++ks)
    w2f[ks] = *(const s8v*)&W2f[(w * 16 + ks) * 512 + lane * 8];

  // stage raw [ag|g|obs|1|0] K=128 in B-frag-major (2 b128 stores/thread)
  {
    const int row = tid & 63;            // adjacent lanes -> adjacent rows
    const int c0  = (tid >> 6) * 16;
    const float* agr = ag  + (size_t)(r0 + row) * 30;
    const float* gr  = g   + (size_t)(r0 + row) * 30;
    const float* obr = obs + (size_t)(r0 + row) * 55;
    union { short s[16]; s8v v[2]; } o;
#pragma unroll
    for (int cc = 0; cc < 16; ++cc) {
      int c = c0 + cc;
      float v;
      if      (c < 30)  v = agr[c];
      else if (c < 60)  v = gr[c - 30];
      else if (c < 115) v = obr[c - 60];
      else if (c == 115) v = 1.0f;
      else              v = 0.0f;
      o.s[cc] = bf16s(v);
    }
    const int base = ((row >> 5) * 8 + (c0 >> 4)) * 512 + (row & 31) * 8;
    *reinterpret_cast<s8v*>(&rawS[base])       = o.v[0];   // k&15 in [0,8)
    *reinterpret_cast<s8v*>(&rawS[base + 256]) = o.v[1];   // k&15 in [8,16)
  }

  f16v agg[2] = {};

  __syncthreads();  // rawS staged

  // GEMM1(pair p) -> Hs[p&1]:  D = W1P[p](A, mt=w) x raw(B); K=128
  auto gemm1 = [&](int p) {
    const __hip_bfloat16* wb = W1P + p * 32768;
    __hip_bfloat16* buf = &Hs[p & 1][0];
    f16v a1[2] = {};
#pragma unroll
    for (int ks = 0; ks < 8; ++ks) {
      s8v w1 = *(const s8v*)&wb[(w * 8 + ks) * 512 + lane * 8];
      s8v rb0 = *(const s8v*)&rawS[ks * 512 + lane * 8];
      s8v rb1 = *(const s8v*)&rawS[(8 + ks) * 512 + lane * 8];
      a1[0] = __builtin_amdgcn_mfma_f32_32x32x16_bf16(w1, rb0, a1[0], 0, 0, 0);
      a1[1] = __builtin_amdgcn_mfma_f32_32x32x16_bf16(w1, rb1, a1[1], 0, 0, 0);
    }
    // epilogue: relu (bias via ones-col); reg-quad g' covers 4 consecutive k
    // hidden col m = 8g' + 4q5 + r -> block ks = w*2 + (g'>>1),
    // k&15 = 8*(g'&1)+4q5+r, lane' = l31 + 32*(g'&1)
#pragma unroll
    for (int nt = 0; nt < 2; ++nt)
#pragma unroll
      for (int gp = 0; gp < 4; ++gp) {
        float v0 = fmaxf(a1[nt][4 * gp + 0], 0.f);
        float v1 = fmaxf(a1[nt][4 * gp + 1], 0.f);
        float v2 = fmaxf(a1[nt][4 * gp + 2], 0.f);
        float v3 = fmaxf(a1[nt][4 * gp + 3], 0.f);
        uint2 U; U.x = pk2(v0, v1); U.y = pk2(v2, v3);
        *reinterpret_cast<uint2*>(
          &buf[(nt * 16 + w * 2 + (gp >> 1)) * 512 +
               (l31 + 32 * (gp & 1)) * 8 + 4 * q5]) = U;
      }
  };

  gemm1(0);
  __syncthreads();

#pragma unroll 1
  for (int p = 0; p < 6; ++p) {
    // GEMM2(p): D = W2(A, mt=w) x H(B); K=256; agg += relu(D + b2)
    const __hip_bfloat16* buf = &Hs[p & 1][0];
    f16v a2[2] = {};
#pragma unroll
    for (int ks = 0; ks < 16; ++ks) {
      s8v h0 = *(const s8v*)&buf[ks * 512 + lane * 8];
      s8v h1 = *(const s8v*)&buf[(16 + ks) * 512 + lane * 8];
      a2[0] = __builtin_amdgcn_mfma_f32_32x32x16_bf16(w2f[ks], h0, a2[0], 0, 0, 0);
      a2[1] = __builtin_amdgcn_mfma_f32_32x32x16_bf16(w2f[ks], h1, a2[1], 0, 0, 0);
    }
#pragma unroll
    for (int nt = 0; nt < 2; ++nt)
#pragma unroll
      for (int e = 0; e < 16; ++e)
        agg[nt][e] += fmaxf(a2[nt][e] + (&b2v[e >> 2].x)[e & 3], 0.f);

    // GEMM1(p+1) into the other buffer (no barrier needed: that buffer's
    // last readers finished GEMM2(p-1) before the previous barrier)
    if (p < 5) gemm1(p + 1);
    __syncthreads();
  }

  // W3 A-frags + b3 (w2f dead)
  s8v w3f[16];
#pragma unroll
  for (int ks = 0; ks < 16; ++ks)
    w3f[ks] = *(const s8v*)&W3f[(w * 16 + ks) * 512 + lane * 8];
  float4 b3v[4];
#pragma unroll
  for (int gidx = 0; gidx < 4; ++gidx)
    b3v[gidx] = *(const float4*)&b3[w * 32 + 8 * gidx + 4 * q5];

  // stash agg (bf16) into Hs[0], B-frag-major (same transform as gemm1 epi)
  {
    __hip_bfloat16* bufA = &Hs[0][0];
#pragma unroll
    for (int nt = 0; nt < 2; ++nt)
#pragma unroll
      for (int gp = 0; gp < 4; ++gp) {
        uint2 U;
        U.x = pk2(agg[nt][4 * gp + 0], agg[nt][4 * gp + 1]);
        U.y = pk2(agg[nt][4 * gp + 2], agg[nt][4 * gp + 3]);
        *reinterpret_cast<uint2*>(
          &bufA[(nt * 16 + w * 2 + (gp >> 1)) * 512 +
                (l31 + 32 * (gp & 1)) * 8 + 4 * q5]) = U;
      }
  }
  __syncthreads();

  // GEMM3: hr = relu(W3(A) x agg(B) + b3); reads Hs[0], writes Hs[1]
  {
    const __hip_bfloat16* bufA = &Hs[0][0];
    f16v a3[2] = {};
#pragma unroll
    for (int ks = 0; ks < 16; ++ks) {
      s8v h0 = *(const s8v*)&bufA[ks * 512 + lane * 8];
      s8v h1 = *(const s8v*)&bufA[(16 + ks) * 512 + lane * 8];
      a3[0] = __builtin_amdgcn_mfma_f32_32x32x16_bf16(w3f[ks], h0, a3[0], 0, 0, 0);
      a3[1] = __builtin_amdgcn_mfma_f32_32x32x16_bf16(w3f[ks], h1, a3[1], 0, 0, 0);
    }
    __hip_bfloat16* bufB = &Hs[1][0];
#pragma unroll
    for (int nt = 0; nt < 2; ++nt)
#pragma unroll
      for (int gp = 0; gp < 4; ++gp) {
        float v0 = fmaxf(a3[nt][4 * gp + 0] + b3v[gp].x, 0.f);
        float v1 = fmaxf(a3[nt][4 * gp + 1] + b3v[gp].y, 0.f);
        float v2 = fmaxf(a3[nt][4 * gp + 2] + b3v[gp].z, 0.f);
        float v3 = fmaxf(a3[nt][4 * gp + 3] + b3v[gp].w, 0.f);
        uint2 U; U.x = pk2(v0, v1); U.y = pk2(v2, v3);
        *reinterpret_cast<uint2*>(
          &bufB[(nt * 16 + w * 2 + (gp >> 1)) * 512 +
                (l31 + 32 * (gp & 1)) * 8 + 4 * q5]) = U;
      }
  }
  __syncthreads();

  // GEMM4: heads; waves 0,1 take batch 32-tile nt=w; reads Hs[1]
  if (w < 2) {
    const __hip_bfloat16* bufB = &Hs[1][0];
    f16v a4 = {};
#pragma unroll
    for (int ks = 0; ks < 16; ++ks) {
      s8v w4 = *(const s8v*)&W4f[ks * 512 + lane * 8];
      s8v hf = *(const s8v*)&bufB[(w * 16 + ks) * 512 + lane * 8];
      a4 = __builtin_amdgcn_mfma_f32_32x32x16_bf16(w4, hf, a4, 0, 0, 0);
    }
    // D: head col m = 4*q5 + r (regs 0..3); batch row = w*32 + l31
    const int row = r0 + w * 32 + l31;
    if (q5 == 0) {            // m=0..3: mean
      float4 mb = *(const float4*)meanb;
      float4 o;
      o.x = a4[0] + mb.x; o.y = a4[1] + mb.y;
      o.z = a4[2] + mb.z; o.w = a4[3] + mb.w;
      *reinterpret_cast<float4*>(&out[(size_t)row * 4]) = o;
    } else {                  // m=4..7: logstd (clipped)
      float4 lb = *(const float4*)logstdb;
      float4 o;
      o.x = fminf(fmaxf(a4[0] + lb.x, -20.f), 2.f);
      o.y = fminf(fmaxf(a4[1] + lb.y, -20.f), 2.f);
      o.z = fminf(fmaxf(a4[2] + lb.z, -20.f), 2.f);
      o.w = fminf(fmaxf(a4[3] + lb.w, -20.f), 2.f);
      *reinterpret_cast<float4*>(&out[(size_t)B_TOTAL * 4 + (size_t)row * 4]) = o;
    }
  }
}

extern "C" void kernel_launch(void* const* d_in, const int* in_sizes, int n_in,
                              void* d_out, int out_size, void* d_ws, size_t ws_size,
                              hipStream_t stream) {
  const float* obs      = (const float*)d_in[0];
  const float* ag       = (const float*)d_in[1];
  const float* g        = (const float*)d_in[2];
  const float* phi_w1   = (const float*)d_in[3];
  const float* phi_b1   = (const float*)d_in[4];
  const float* phi_w2   = (const float*)d_in[5];
  const float* phi_b2   = (const float*)d_in[6];
  const float* rho_w1   = (const float*)d_in[7];
  const float* rho_b1   = (const float*)d_in[8];
  const float* mean_w   = (const float*)d_in[9];
  const float* mean_b   = (const float*)d_in[10];
  const float* logstd_w = (const float*)d_in[11];
  const float* logstd_b = (const float*)d_in[12];
  float* out = (float*)d_out;

  // ws (bf16): W1P 6x32768 | W2f 65536 | W3f 65536 | W4f 8192 elems
  char* ws = (char*)d_ws;
  __hip_bfloat16* W1P = (__hip_bfloat16*)(ws);
  __hip_bfloat16* W2f = (__hip_bfloat16*)(ws + 393216);
  __hip_bfloat16* W3f = (__hip_bfloat16*)(ws + 393216 + 131072);
  __hip_bfloat16* W4f = (__hip_bfloat16*)(ws + 393216 + 262144);

  prep_weights<<<164, 256, 0, stream>>>(phi_w1, phi_b1, phi_w2, rho_w1,
                                        mean_w, logstd_w, W1P, W2f, W3f, W4f);
  actor_main<<<B_TOTAL / TROWS, 512, 0, stream>>>(
      obs, ag, g, W1P, W2f, W3f, W4f, phi_b2, rho_b1, mean_b, logstd_b, out);
}